// Round 13
// baseline (1339.008 us; speedup 1.0000x reference)
//
#include <hip/hip_runtime.h>
#include <hip/hip_bf16.h>
#include <stdint.h>

// Problem: LELayer_54022098649764 — f32 inputs.
// x: [16384,512] f32, A: [512,512] f32; out: [16384,512] f32 =
//   sum over 10 nearest neighbors (euclidean, excl self, np-f32 semantics) of xW = x@A.
//
// R13 vs R12 (1197 us; knn_coarse 1012 us, VGPR 64, WRITE 140 MB unchanged):
//  - R12 proved the spill is NOT the epilogue scan (sequentialized scan changed
//    nothing). The spill is k-loop register pressure: at (256,4) budget=128,
//    acc[4][4]=64 AGPR leaves 64 arch for 32 frag regs + addressing -> ~133 MB
//    scratch round-trips per dispatch INSIDE the kstep loop.
//  - Structural fix: 512-thread blocks (8 waves), wave grid 2 rows x 4 cols,
//    each wave owns 64x32 = acc[4][2] = 32 AGPR -> 96 arch regs at 4 waves/EU:
//    no spill. NPART 8->4 keeps grid = 512 blocks = 2 blocks/CU x 8 waves =
//    16 waves/CU (same as R7) in ONE dispatch wave.
//  - Staging: 2 global_load_lds per thread per kstep (A row + B row), linear
//    dst = tid*8, source-swizzle sstk=((tid&3)^((tid>>3)&3))*8 (same involution
//    as before; read-side pq8 unchanged since wc in {0,32,64,96} are 0 mod 4
//    after >>1). vmcnt ledger: prologue 4 in flight, steady WAITVM(2).
//  - Rerank back to the R5-verified 4x13=52-candidate config (RCAND=20).
//  - Keeps: hh-only coarse + exact rerank, packed (qd<<14|col) top-13 lists,
//    counted-vmcnt, XCD remap, setprio, strip-min scan.

typedef _Float16 f16x8 __attribute__((ext_vector_type(8)));
typedef float f32x4 __attribute__((ext_vector_type(4)));

#define NPTS 16384
#define DIM 512
#define KNN 10
#define TILE 128
#define BK 32
#define NPART 4
#define PARTC (NPTS / NPART)      // 4096
#define NCT (PARTC / TILE)        // 32
#define NKC (DIM / BK)            // 16
#define SET_H (TILE * BK)         // 4096 halfs per tile
#define D2PAD 36
#define CLIST 13                  // coarse candidates per part
#define NCAND (NPART * CLIST)     // 52
#define RCAND 20                  // reranked candidates

// ws layout (bytes), total ~68.2 MB
//  liveness: aht/alt: split_at -> xw | xh: split_x -> knn_coarse |
//  xl: split_x -> xw | pk(=xl): knn_coarse -> rerank | idx(=xh): rerank -> gather
#define OFF_SQ   0u
#define OFF_AHT  65536u
#define OFF_ALT  (OFF_AHT + 524288u)
#define OFF_XH   (OFF_ALT + 524288u)           // 16 MB
#define OFF_IDX  OFF_XH                        // alias
#define OFF_XL   (OFF_XH + 16777216u)          // 16 MB
#define OFF_PK   OFF_XL                        // alias: 4*16384*13*4 = 3.4 MB
#define OFF_XW   (OFF_XL + 16777216u)          // 32 MB

#define GLDS16(g, l) __builtin_amdgcn_global_load_lds( \
    (__attribute__((address_space(1))) const void*)(g), \
    (__attribute__((address_space(3))) void*)(l), 16, 0, 0)

#define WAITVM(N) do { asm volatile("s_waitcnt vmcnt(" #N ")" ::: "memory"); \
                       __builtin_amdgcn_sched_barrier(0); } while (0)
#define WAITLGKM0 do { asm volatile("s_waitcnt lgkmcnt(0)" ::: "memory"); \
                       __builtin_amdgcn_sched_barrier(0); } while (0)

__device__ __forceinline__ float4 min4(float4 a, float4 b) {
  return make_float4(fminf(a.x, b.x), fminf(a.y, b.y), fminf(a.z, b.z), fminf(a.w, b.w));
}

// Full split staging (xw_kernel, 256 thr): [Ah, Al, Bh, Bl] tiles, 8 loads/thread.
__device__ __forceinline__ void stage_tiles(const _Float16* __restrict__ ah,
                                            const _Float16* __restrict__ al,
                                            const _Float16* __restrict__ bh,
                                            const _Float16* __restrict__ bl,
                                            int ar0, int br0, int k0,
                                            _Float16* set, int wv, int lane, int sstk) {
  const int strow = wv * 16 + (lane >> 2);
#pragma unroll
  for (int q = 0; q < 2; q++) {
    const int row = q * 64 + strow;
    const int dst = q * 2048 + wv * 512 + lane * 8;
    const size_t ga = (size_t)(ar0 + row) * DIM + k0 + sstk;
    const size_t gb = (size_t)(br0 + row) * DIM + k0 + sstk;
    GLDS16(ah + ga, set + dst);
    GLDS16(al + ga, set + SET_H + dst);
    GLDS16(bh + gb, set + 2 * SET_H + dst);
    GLDS16(bl + gb, set + 3 * SET_H + dst);
  }
}

// hh-only staging (knn_coarse, 512 thr): [Ah, Bh], 2 loads/thread.
// thread t covers row t>>2, phys chunk t&3 -> linear dst t*8; global source
// column pre-swizzled so phys chunk p of row R holds logical chunk p^((R>>1)&3).
__device__ __forceinline__ void stage_h512(const _Float16* __restrict__ xh,
                                           int ar0, int br0, int k0,
                                           _Float16* set, int strow, int sdst, int sstk) {
  GLDS16(xh + (size_t)(ar0 + strow) * DIM + k0 + sstk, set + sdst);
  GLDS16(xh + (size_t)(br0 + strow) * DIM + k0 + sstk, set + SET_H + sdst);
}

// ---------------- k0: split x -> xh,xl (f16) and sq (f32) ----------------
__global__ __launch_bounds__(64) void split_x_kernel(const float* __restrict__ x,
                                                     _Float16* __restrict__ xh,
                                                     _Float16* __restrict__ xl,
                                                     float* __restrict__ sq) {
  const int row = blockIdx.x, tid = threadIdx.x;
  const float4* p = (const float4*)(x + (size_t)row * DIM);
  float4 a = p[tid * 2], b = p[tid * 2 + 1];
  float v[8] = {a.x, a.y, a.z, a.w, b.x, b.y, b.z, b.w};
  f16x8 h, l;
  float s = 0.f;
#pragma unroll
  for (int i = 0; i < 8; i++) {
    _Float16 hi = (_Float16)v[i];
    h[i] = hi;
    l[i] = (_Float16)(v[i] - (float)hi);
    s += v[i] * v[i];
  }
  *(f16x8*)(xh + (size_t)row * DIM + tid * 8) = h;
  *(f16x8*)(xl + (size_t)row * DIM + tid * 8) = l;
#pragma unroll
  for (int off = 32; off > 0; off >>= 1) s += __shfl_down(s, off);
  if (tid == 0) sq[row] = s;
}

// ---------------- k0b: split+transpose A -> AhT,AlT [n][k] f16 ----------------
__global__ __launch_bounds__(64) void split_at_kernel(const float* __restrict__ A,
                                                      _Float16* __restrict__ aht,
                                                      _Float16* __restrict__ alt) {
  const int n = blockIdx.x, tid = threadIdx.x;
#pragma unroll
  for (int i = 0; i < DIM / 64; i++) {
    const int k = i * 64 + tid;
    float v = A[(size_t)k * DIM + n];
    _Float16 h = (_Float16)v;
    aht[(size_t)n * DIM + k] = h;
    alt[(size_t)n * DIM + k] = (_Float16)(v - (float)h);
  }
}

// ---------------- k2: xW = x @ A via 3-MFMA f16 split, f32 out ----------------
__global__ __launch_bounds__(256, 2) void xw_kernel(const _Float16* __restrict__ xh,
                                                    const _Float16* __restrict__ xl,
                                                    const _Float16* __restrict__ aht,
                                                    const _Float16* __restrict__ alt,
                                                    float* __restrict__ xw) {
  __shared__ __align__(16) _Float16 stage[2][4 * SET_H];  // 64 KB
  const int tid = threadIdx.x;
  const int nb = blockIdx.x & 3;
  const int rbk = blockIdx.x >> 2;
  const int r0 = rbk * TILE, n0 = nb * TILE;
  const int wv = tid >> 6, lane = tid & 63;
  const int wr = (wv & 1) * 64, wc = (wv >> 1) * 64;
  const int cl = lane & 15, quad = lane >> 4;
  const int sstk = ((lane & 3) ^ ((lane >> 3) & 3)) * 8;
  const int pq8 = (quad ^ ((cl >> 1) & 3)) * 8;

  f32x4 acc[4][4];
#pragma unroll
  for (int i = 0; i < 4; i++)
#pragma unroll
    for (int j = 0; j < 4; j++) acc[i][j] = (f32x4){0.f, 0.f, 0.f, 0.f};

  stage_tiles(xh, xl, aht, alt, r0, n0, 0, stage[0], wv, lane, sstk);
  __syncthreads();

#pragma unroll 2
  for (int kc = 0; kc < NKC; kc++) {
    if (kc + 1 < NKC)
      stage_tiles(xh, xl, aht, alt, r0, n0, (kc + 1) * BK, stage[(kc + 1) & 1], wv, lane, sstk);
    const _Float16* S = stage[kc & 1];
    f16x8 ah[4], al[4], bh[4], bl[4];
#pragma unroll
    for (int i = 0; i < 4; i++) {
      ah[i] = *(const f16x8*)(S + (wr + i * 16 + cl) * BK + pq8);
      al[i] = *(const f16x8*)(S + SET_H + (wr + i * 16 + cl) * BK + pq8);
    }
#pragma unroll
    for (int j = 0; j < 4; j++) {
      bh[j] = *(const f16x8*)(S + 2 * SET_H + (wc + j * 16 + cl) * BK + pq8);
      bl[j] = *(const f16x8*)(S + 3 * SET_H + (wc + j * 16 + cl) * BK + pq8);
    }
#pragma unroll
    for (int i = 0; i < 4; i++)
#pragma unroll
      for (int j = 0; j < 4; j++) {
        acc[i][j] = __builtin_amdgcn_mfma_f32_16x16x32_f16(ah[i], bh[j], acc[i][j], 0, 0, 0);
        acc[i][j] = __builtin_amdgcn_mfma_f32_16x16x32_f16(ah[i], bl[j], acc[i][j], 0, 0, 0);
        acc[i][j] = __builtin_amdgcn_mfma_f32_16x16x32_f16(al[i], bh[j], acc[i][j], 0, 0, 0);
      }
    __syncthreads();
  }
#pragma unroll
  for (int i = 0; i < 4; i++)
#pragma unroll
    for (int r = 0; r < 4; r++) {
      const int row = r0 + wr + i * 16 + quad * 4 + r;
#pragma unroll
      for (int j = 0; j < 4; j++)
        xw[(size_t)row * DIM + n0 + wc + j * 16 + cl] = acc[i][j][r];
    }
}

// ---------------- k3: COARSE distances (hh only) + packed top-13 per part ----
// 512 threads, 8 waves as 2 (row) x 4 (col): wave owns 64x32 -> acc[4][2] =
// 32 AGPR, leaving 96 arch regs at 4 waves/EU -> no spill.
__global__ __launch_bounds__(512, 4) void knn_coarse_kernel(const _Float16* __restrict__ xh,
                                                            const float* __restrict__ sq,
                                                            unsigned int* __restrict__ pk) {
  __shared__ __align__(16) _Float16 stage[2][2 * SET_H];  // 32 KB (aliased d2buf)
  __shared__ unsigned int listp[TILE][CLIST];             // 6656 B, packed (qd<<14|col)
  __shared__ float sqA[TILE], sqB[TILE];                  // 1 KB  => 40448 B total

  const int tid = threadIdx.x;
  // XCD-aware remap (bijective over 512 blocks): XCD k hosts b%8==k ->
  // 16 consecutive row-tiles per XCD (2 MB A-side L2-resident), parts mixed.
  const int b = blockIdx.x;
  const int rb = (b & 7) * 16 + ((b >> 3) & 15);
  const int part = b >> 7;             // 0..3
  const int r0 = rb * TILE;
  const int cbase = part * PARTC;

  if (tid < TILE) {
    sqA[tid] = sq[r0 + tid];
#pragma unroll
    for (int q = 0; q < CLIST; q++) listp[tid][q] = 0xFFFFFFFFu;
  }
  float th = 4096.0f;  // upper bound on acceptable d2 (packed top unpacked+1)/64

  const int wv = tid >> 6, lane = tid & 63;
  const int wr = (wv & 1) * 64;        // wave row: 0 / 64
  const int wc = (wv >> 1) * 32;       // wave col: 0/32/64/96
  const int cl = lane & 15, quad = lane >> 4;
  const int strow = tid >> 2;          // staged row 0..127
  const int sdst = tid * 8;            // linear LDS dst (halfs)
  const int sstk = ((tid & 3) ^ ((tid >> 3) & 3)) * 8;   // pre-swizzled src chunk
  const int pq8 = (quad ^ ((cl >> 1) & 3)) * 8;          // swizzled read chunk

  float* d2buf = (float*)stage;  // 18,432 B; used only after k-loop drained

  f32x4 acc[4][2];

  for (int ct = 0; ct < NCT; ct++) {
    const int c0 = cbase + ct * TILE;
    __syncthreads();  // prev epilogue done reading d2buf/sqB
    if (tid < TILE) sqB[tid] = sq[c0 + tid];
#pragma unroll
    for (int i = 0; i < 4; i++)
#pragma unroll
      for (int j = 0; j < 2; j++) acc[i][j] = (f32x4){0.f, 0.f, 0.f, 0.f};

    // prologue: 4 loads in flight (2 stages x 2); counted waits retire in order.
    stage_h512(xh, r0, c0, 0, stage[0], strow, sdst, sstk);
    stage_h512(xh, r0, c0, BK, stage[1], strow, sdst, sstk);

    for (int kc = 0; kc < NKC; kc++) {
      if (kc < NKC - 1) { WAITVM(2); } else { WAITVM(0); }
      __builtin_amdgcn_s_barrier();  // buf[kc] landed for all waves

      const _Float16* S = stage[kc & 1];
      f16x8 ah[4], bh[2];
#pragma unroll
      for (int i = 0; i < 4; i++)
        ah[i] = *(const f16x8*)(S + (wr + i * 16 + cl) * BK + pq8);
#pragma unroll
      for (int j = 0; j < 2; j++)
        bh[j] = *(const f16x8*)(S + SET_H + (wc + j * 16 + cl) * BK + pq8);
      WAITLGKM0;
      __builtin_amdgcn_s_barrier();  // all waves done reading buf[kc]

      if (kc + 2 < NKC)
        stage_h512(xh, r0, c0, (kc + 2) * BK, stage[kc & 1], strow, sdst, sstk);

      __builtin_amdgcn_s_setprio(1);
#pragma unroll
      for (int i = 0; i < 4; i++)
#pragma unroll
        for (int j = 0; j < 2; j++)
          acc[i][j] = __builtin_amdgcn_mfma_f32_16x16x32_f16(ah[i], bh[j], acc[i][j], 0, 0, 0);
      __builtin_amdgcn_s_setprio(0);
    }
    // vmcnt==0, all frag reads done -> stage reusable as d2buf.

    // 4 passes over 32-col strips: waves with (wv>>1)==p dump their 64x32
    // quadrant (both row halves), then owner threads (tid<128) scan.
#pragma unroll
    for (int p = 0; p < 4; p++) {
      if ((wv >> 1) == p) {
#pragma unroll
        for (int j = 0; j < 2; j++) {
          const float sb = sqB[wc + j * 16 + cl];
#pragma unroll
          for (int i = 0; i < 4; i++)
#pragma unroll
            for (int r = 0; r < 4; r++) {
              const int row = wr + i * 16 + quad * 4 + r;
              d2buf[row * D2PAD + j * 16 + cl] =
                  fmaxf(sqA[row] + sb - 2.0f * acc[i][j][r], 0.0f);
            }
        }
      }
      __syncthreads();
      if (tid < TILE) {
        const int rg = r0 + tid;
        const float* drow = d2buf + tid * D2PAD;
        const float4 v0 = *(const float4*)(drow + 0), v1 = *(const float4*)(drow + 4);
        const float4 v2 = *(const float4*)(drow + 8), v3 = *(const float4*)(drow + 12);
        const float4 v4 = *(const float4*)(drow + 16), v5 = *(const float4*)(drow + 20);
        const float4 v6 = *(const float4*)(drow + 24), v7 = *(const float4*)(drow + 28);
        const float4 ma = min4(min4(min4(v0, v1), min4(v2, v3)),
                               min4(min4(v4, v5), min4(v6, v7)));
        const float mmin = fminf(fminf(ma.x, ma.y), fminf(ma.z, ma.w));
        // reject iff qd(mmin) > top_qd: mmin*64 >= top_qd+1 == th*64  (safe)
        if (mmin < th) {
          for (int c = 0; c < 32; c++) {
            const float d2v = drow[c];
            if (d2v >= th) continue;
            const int cg = c0 + p * 32 + c;
            if (cg == rg) continue;
            const unsigned int qd = (unsigned int)(d2v * 64.0f);  // d2<4096 -> 18b
            const unsigned int pv = (qd << 14) | (unsigned int)cg;
            if (pv < listp[tid][CLIST - 1]) {
              int pp = CLIST - 1;
              while (pp > 0 && listp[tid][pp - 1] > pv) {
                listp[tid][pp] = listp[tid][pp - 1];
                pp--;
              }
              listp[tid][pp] = pv;
              th = (float)((listp[tid][CLIST - 1] >> 14) + 1) * 0.015625f;
            }
          }
        }
      }
      __syncthreads();
    }
  }

  if (tid < TILE) {
    const unsigned int base = ((unsigned int)part * NPTS + (r0 + tid)) * CLIST;
#pragma unroll
    for (int q = 0; q < CLIST; q++) pk[base + q] = listp[tid][q];
  }
}

// ---------------- k4: exact rerank of merged top-RCAND of 52 candidates --------
__global__ __launch_bounds__(64) void rerank_kernel(const float* __restrict__ x,
                                                    const float* __restrict__ sq,
                                                    const unsigned int* __restrict__ pk,
                                                    int* __restrict__ idx) {
  __shared__ unsigned int pkL[64];
  __shared__ unsigned short candL[RCAND];
  const int row = blockIdx.x, lane = threadIdx.x;

  // load the 4x13 packed coarse candidates (values unique: low 14 bits = col)
  if (lane < NCAND) {
    const int part = lane / CLIST, pos = lane - part * CLIST;
    pkL[lane] = pk[((size_t)part * NPTS + row) * CLIST + pos];
  } else {
    pkL[lane] = 0xFFFFFFFFu;
  }
  __syncthreads();

  // rank-select top-RCAND of 52
  const unsigned int v = pkL[lane];
  int rank = 0;
#pragma unroll
  for (int s = 0; s < NCAND; s++) rank += (pkL[s] < v) ? 1 : 0;
  if (lane < NCAND && rank < RCAND) candL[rank] = (unsigned short)(v & 0x3FFFu);
  __syncthreads();

  // own row stash: 8 f32/lane
  const float4 xa = *(const float4*)(x + (size_t)row * DIM + lane * 8);
  const float4 xb = *(const float4*)(x + (size_t)row * DIM + lane * 8 + 4);
  const float sqr = sq[row];

  float dl[KNN]; int il[KNN];
#pragma unroll
  for (int q = 0; q < KNN; q++) { dl[q] = INFINITY; il[q] = 0x7fffffff; }

  for (int k = 0; k < RCAND; k++) {
    const int c = candL[k];
    const float4 ya = *(const float4*)(x + (size_t)c * DIM + lane * 8);
    const float4 yb = *(const float4*)(x + (size_t)c * DIM + lane * 8 + 4);
    float p = xa.x * ya.x;
    p = fmaf(xa.y, ya.y, p); p = fmaf(xa.z, ya.z, p); p = fmaf(xa.w, ya.w, p);
    p = fmaf(xb.x, yb.x, p); p = fmaf(xb.y, yb.y, p);
    p = fmaf(xb.z, yb.z, p); p = fmaf(xb.w, yb.w, p);
#pragma unroll
    for (int off = 32; off > 0; off >>= 1) p += __shfl_xor(p, off);
    const float d2 = sqr + sq[c] - 2.0f * p;
    float dd = sqrtf(fmaxf(d2, 0.0f));  // exact reference domain
    int cc = c;
    // swap-chain insertion, tie-break: smaller index first (top_k stability)
#pragma unroll
    for (int q = 0; q < KNN; q++) {
      const bool better = (dd < dl[q]) || (dd == dl[q] && cc < il[q]);
      const float nd = better ? dl[q] : dd;
      const int ni = better ? il[q] : cc;
      dl[q] = better ? dd : dl[q];
      il[q] = better ? cc : il[q];
      dd = nd; cc = ni;
    }
  }
  if (lane == 0) {
#pragma unroll
    for (int q = 0; q < KNN; q++) idx[(size_t)row * KNN + q] = il[q];
  }
}

// ---------------- k5: gather-sum of 10 neighbor rows of xW (f32) ----------------
__global__ __launch_bounds__(128) void gather_kernel(const float* __restrict__ xw,
                                                     const int* __restrict__ idx,
                                                     float* __restrict__ out) {
  const int row = blockIdx.x, tid = threadIdx.x;
  const int* ip = idx + (size_t)row * KNN;
  float4 s = {0.f, 0.f, 0.f, 0.f};
#pragma unroll
  for (int j = 0; j < KNN; j++) {
    const int nb = ip[j] & (NPTS - 1);
    const float4 v = *(const float4*)(xw + (size_t)nb * DIM + tid * 4);
    s.x += v.x; s.y += v.y; s.z += v.z; s.w += v.w;
  }
  *(float4*)(out + (size_t)row * DIM + tid * 4) = s;
}

extern "C" void kernel_launch(void* const* d_in, const int* in_sizes, int n_in,
                              void* d_out, int out_size, void* d_ws, size_t ws_size,
                              hipStream_t stream) {
  const float* x = (const float*)d_in[0];
  const float* A = (const float*)d_in[1];
  float* out = (float*)d_out;
  char* ws = (char*)d_ws;
  float* sq = (float*)(ws + OFF_SQ);
  unsigned int* pk = (unsigned int*)(ws + OFF_PK);
  int* idx = (int*)(ws + OFF_IDX);
  _Float16* xh = (_Float16*)(ws + OFF_XH);
  _Float16* xl = (_Float16*)(ws + OFF_XL);
  _Float16* aht = (_Float16*)(ws + OFF_AHT);
  _Float16* alt = (_Float16*)(ws + OFF_ALT);
  float* xw = (float*)(ws + OFF_XW);

  split_x_kernel<<<NPTS, 64, 0, stream>>>(x, xh, xl, sq);
  split_at_kernel<<<DIM, 64, 0, stream>>>(A, aht, alt);
  xw_kernel<<<(NPTS / TILE) * (DIM / TILE), 256, 0, stream>>>(xh, xl, aht, alt, xw);
  knn_coarse_kernel<<<NPART * (NPTS / TILE), 512, 0, stream>>>(xh, sq, pk);
  rerank_kernel<<<NPTS, 64, 0, stream>>>(x, sq, pk, idx);
  gather_kernel<<<NPTS, 128, 0, stream>>>(xw, idx, out);
}

// Round 16
// 1220.610 us; speedup vs baseline: 1.0970x; 1.0970x over previous
//
#include <hip/hip_runtime.h>
#include <hip/hip_bf16.h>
#include <stdint.h>

// Problem: LELayer_54022098649764 — f32 inputs.
// x: [16384,512] f32, A: [512,512] f32; out: [16384,512] f32 =
//   sum over 10 nearest neighbors (euclidean, excl self, np-f32 semantics) of xW = x@A.
//
// R16 == R14/R15 resubmission (both failed on GPU acquisition infra, not the kernel).
// R14 vs R13 (1339; knn 1205, spill GONE but slower) / R12 (1197; knn 1012):
//  - R13 proved spill was off the critical path. The floor is the fixed cost
//    of each barrier-paired kstep slot (~2.4-5k cy regardless of config).
//  - Fix: amortize — TILE_R 128->256. Block output 256x128: chip-wide
//    block-ksteps HALVE (262144 -> 512 blocks x 16 ct x 16 kc = 131072) at the
//    same per-kstep shape. 512 thr = 8 waves (4 row-groups x 2 col-halves),
//    acc[4][4]=64 AGPR. LDS 62.5 KB -> 2 blocks/CU, grid 512 = ONE dispatch
//    wave, 16 waves/CU.
//  - Staging: A 2 loads + B 1 load per thread per kstep (dst=q*4096+tid*8 /
//    tid*8; source swizzle sstk=((tid&3)^((tid>>3)&3))*8, read pq8 unchanged —
//    wr, i*16, wc all 0 mod 8 so (row>>1)&3 == (cl>>1)&3). vmcnt ledger:
//    prologue 6 in flight, steady WAITVM(3), drain 0 at kc=15.
//  - rerank/xw/splits/gather identical to R12 (passed, absmax 1.0).

typedef _Float16 f16x8 __attribute__((ext_vector_type(8)));
typedef float f32x4 __attribute__((ext_vector_type(4)));

#define NPTS 16384
#define DIM 512
#define KNN 10
#define TILE 128                  // xw_kernel tile (unchanged)
#define TR 256                    // knn_coarse row tile
#define TC 128                    // knn_coarse col tile
#define BK 32
#define NPART 8
#define PARTC (NPTS / NPART)      // 2048
#define NCT (PARTC / TC)          // 16
#define NKC (DIM / BK)            // 16
#define SET_H (TILE * BK)         // xw staging tile halfs (4096)
#define A_H (TR * BK)             // 8192 halfs (16 KB)
#define B_H (TC * BK)             // 4096 halfs (8 KB)
#define SET_HH (A_H + B_H)        // 12288 halfs per knn set (24 KB)
#define D2PAD 36
#define CLIST 13
#define NCAND (NPART * CLIST)     // 104
#define RCAND 20

// ws layout (bytes), total ~68.2 MB (same as R12)
#define OFF_SQ   0u
#define OFF_AHT  65536u
#define OFF_ALT  (OFF_AHT + 524288u)
#define OFF_XH   (OFF_ALT + 524288u)           // 16 MB
#define OFF_IDX  OFF_XH                        // alias
#define OFF_XL   (OFF_XH + 16777216u)          // 16 MB
#define OFF_PK   OFF_XL                        // alias: 8*16384*13*4 = 6.8 MB
#define OFF_XW   (OFF_XL + 16777216u)          // 32 MB

#define GLDS16(g, l) __builtin_amdgcn_global_load_lds( \
    (__attribute__((address_space(1))) const void*)(g), \
    (__attribute__((address_space(3))) void*)(l), 16, 0, 0)

#define WAITVM(N) do { asm volatile("s_waitcnt vmcnt(" #N ")" ::: "memory"); \
                       __builtin_amdgcn_sched_barrier(0); } while (0)
#define WAITLGKM0 do { asm volatile("s_waitcnt lgkmcnt(0)" ::: "memory"); \
                       __builtin_amdgcn_sched_barrier(0); } while (0)

__device__ __forceinline__ float4 min4(float4 a, float4 b) {
  return make_float4(fminf(a.x, b.x), fminf(a.y, b.y), fminf(a.z, b.z), fminf(a.w, b.w));
}

// Full split staging (xw_kernel, 256 thr): [Ah, Al, Bh, Bl], 8 loads/thread.
__device__ __forceinline__ void stage_tiles(const _Float16* __restrict__ ah,
                                            const _Float16* __restrict__ al,
                                            const _Float16* __restrict__ bh,
                                            const _Float16* __restrict__ bl,
                                            int ar0, int br0, int k0,
                                            _Float16* set, int wv, int lane, int sstk) {
  const int strow = wv * 16 + (lane >> 2);
#pragma unroll
  for (int q = 0; q < 2; q++) {
    const int row = q * 64 + strow;
    const int dst = q * 2048 + wv * 512 + lane * 8;
    const size_t ga = (size_t)(ar0 + row) * DIM + k0 + sstk;
    const size_t gb = (size_t)(br0 + row) * DIM + k0 + sstk;
    GLDS16(ah + ga, set + dst);
    GLDS16(al + ga, set + SET_H + dst);
    GLDS16(bh + gb, set + 2 * SET_H + dst);
    GLDS16(bl + gb, set + 3 * SET_H + dst);
  }
}

// knn_coarse staging (512 thr): A tile 256x32 (2 loads) + B tile 128x32 (1).
// Linear dst; global source column pre-swizzled (phys chunk p of row R holds
// logical chunk p^((R>>1)&3)).
__device__ __forceinline__ void stage_rc(const _Float16* __restrict__ xh,
                                         int ar0, int br0, int k0,
                                         _Float16* set, int tid, int sstk) {
  const int r4 = tid >> 2;           // 0..127
#pragma unroll
  for (int q = 0; q < 2; q++)
    GLDS16(xh + (size_t)(ar0 + q * 128 + r4) * DIM + k0 + sstk, set + q * 4096 + tid * 8);
  GLDS16(xh + (size_t)(br0 + r4) * DIM + k0 + sstk, set + A_H + tid * 8);
}

// ---------------- k0: split x -> xh,xl (f16) and sq (f32) ----------------
__global__ __launch_bounds__(64) void split_x_kernel(const float* __restrict__ x,
                                                     _Float16* __restrict__ xh,
                                                     _Float16* __restrict__ xl,
                                                     float* __restrict__ sq) {
  const int row = blockIdx.x, tid = threadIdx.x;
  const float4* p = (const float4*)(x + (size_t)row * DIM);
  float4 a = p[tid * 2], b = p[tid * 2 + 1];
  float v[8] = {a.x, a.y, a.z, a.w, b.x, b.y, b.z, b.w};
  f16x8 h, l;
  float s = 0.f;
#pragma unroll
  for (int i = 0; i < 8; i++) {
    _Float16 hi = (_Float16)v[i];
    h[i] = hi;
    l[i] = (_Float16)(v[i] - (float)hi);
    s += v[i] * v[i];
  }
  *(f16x8*)(xh + (size_t)row * DIM + tid * 8) = h;
  *(f16x8*)(xl + (size_t)row * DIM + tid * 8) = l;
#pragma unroll
  for (int off = 32; off > 0; off >>= 1) s += __shfl_down(s, off);
  if (tid == 0) sq[row] = s;
}

// ---------------- k0b: split+transpose A -> AhT,AlT [n][k] f16 ----------------
__global__ __launch_bounds__(64) void split_at_kernel(const float* __restrict__ A,
                                                      _Float16* __restrict__ aht,
                                                      _Float16* __restrict__ alt) {
  const int n = blockIdx.x, tid = threadIdx.x;
#pragma unroll
  for (int i = 0; i < DIM / 64; i++) {
    const int k = i * 64 + tid;
    float v = A[(size_t)k * DIM + n];
    _Float16 h = (_Float16)v;
    aht[(size_t)n * DIM + k] = h;
    alt[(size_t)n * DIM + k] = (_Float16)(v - (float)h);
  }
}

// ---------------- k2: xW = x @ A via 3-MFMA f16 split, f32 out ----------------
__global__ __launch_bounds__(256, 2) void xw_kernel(const _Float16* __restrict__ xh,
                                                    const _Float16* __restrict__ xl,
                                                    const _Float16* __restrict__ aht,
                                                    const _Float16* __restrict__ alt,
                                                    float* __restrict__ xw) {
  __shared__ __align__(16) _Float16 stage[2][4 * SET_H];  // 64 KB
  const int tid = threadIdx.x;
  const int nb = blockIdx.x & 3;
  const int rbk = blockIdx.x >> 2;
  const int r0 = rbk * TILE, n0 = nb * TILE;
  const int wv = tid >> 6, lane = tid & 63;
  const int wr = (wv & 1) * 64, wc = (wv >> 1) * 64;
  const int cl = lane & 15, quad = lane >> 4;
  const int sstk = ((lane & 3) ^ ((lane >> 3) & 3)) * 8;
  const int pq8 = (quad ^ ((cl >> 1) & 3)) * 8;

  f32x4 acc[4][4];
#pragma unroll
  for (int i = 0; i < 4; i++)
#pragma unroll
    for (int j = 0; j < 4; j++) acc[i][j] = (f32x4){0.f, 0.f, 0.f, 0.f};

  stage_tiles(xh, xl, aht, alt, r0, n0, 0, stage[0], wv, lane, sstk);
  __syncthreads();

#pragma unroll 2
  for (int kc = 0; kc < NKC; kc++) {
    if (kc + 1 < NKC)
      stage_tiles(xh, xl, aht, alt, r0, n0, (kc + 1) * BK, stage[(kc + 1) & 1], wv, lane, sstk);
    const _Float16* S = stage[kc & 1];
    f16x8 ah[4], al[4], bh[4], bl[4];
#pragma unroll
    for (int i = 0; i < 4; i++) {
      ah[i] = *(const f16x8*)(S + (wr + i * 16 + cl) * BK + pq8);
      al[i] = *(const f16x8*)(S + SET_H + (wr + i * 16 + cl) * BK + pq8);
    }
#pragma unroll
    for (int j = 0; j < 4; j++) {
      bh[j] = *(const f16x8*)(S + 2 * SET_H + (wc + j * 16 + cl) * BK + pq8);
      bl[j] = *(const f16x8*)(S + 3 * SET_H + (wc + j * 16 + cl) * BK + pq8);
    }
#pragma unroll
    for (int i = 0; i < 4; i++)
#pragma unroll
      for (int j = 0; j < 4; j++) {
        acc[i][j] = __builtin_amdgcn_mfma_f32_16x16x32_f16(ah[i], bh[j], acc[i][j], 0, 0, 0);
        acc[i][j] = __builtin_amdgcn_mfma_f32_16x16x32_f16(ah[i], bl[j], acc[i][j], 0, 0, 0);
        acc[i][j] = __builtin_amdgcn_mfma_f32_16x16x32_f16(al[i], bh[j], acc[i][j], 0, 0, 0);
      }
    __syncthreads();
  }
#pragma unroll
  for (int i = 0; i < 4; i++)
#pragma unroll
    for (int r = 0; r < 4; r++) {
      const int row = r0 + wr + i * 16 + quad * 4 + r;
#pragma unroll
      for (int j = 0; j < 4; j++)
        xw[(size_t)row * DIM + n0 + wc + j * 16 + cl] = acc[i][j][r];
    }
}

// ---------------- k3: COARSE distances (hh only), 256x128 block tile ----------
// 512 thr = 8 waves: wv&3 = row-group (64 rows), wv>>2 = col-half (64 cols).
__global__ __launch_bounds__(512, 4) void knn_coarse_kernel(const _Float16* __restrict__ xh,
                                                            const float* __restrict__ sq,
                                                            unsigned int* __restrict__ pk) {
  __shared__ __align__(16) _Float16 stage[2][SET_HH];     // 48 KB (d2buf aliases)
  __shared__ unsigned int listp[TR][CLIST];               // 13312 B
  __shared__ float sqA[TR], sqB[TC];                      // 1.5 KB => 62.5 KB total

  const int tid = threadIdx.x;
  // XCD remap (bijective over 512 blocks): 64 row-tiles permuted, part = b>>6.
  const int b = blockIdx.x;
  const int rbt = (b & 7) * 8 + ((b >> 3) & 7);
  const int part = b >> 6;
  const int r0 = rbt * TR;
  const int cbase = part * PARTC;

  if (tid < TR) {
    sqA[tid] = sq[r0 + tid];
#pragma unroll
    for (int q = 0; q < CLIST; q++) listp[tid][q] = 0xFFFFFFFFu;
  }
  float th = 4096.0f;  // (top_qd+1)/64 upper bound on acceptable d2

  const int wv = tid >> 6, lane = tid & 63;
  const int wr = (wv & 3) * 64;       // row group 0/64/128/192
  const int wc = (wv >> 2) * 64;      // col half 0/64
  const int cl = lane & 15, quad = lane >> 4;
  const int sstk = ((tid & 3) ^ ((tid >> 3) & 3)) * 8;   // pre-swizzled src chunk
  const int pq8 = (quad ^ ((cl >> 1) & 3)) * 8;          // swizzled read chunk

  float* d2buf = (float*)stage;  // 256*36*4 = 36864 B <= 48 KB; post-drain only

  f32x4 acc[4][4];

  for (int ct = 0; ct < NCT; ct++) {
    const int c0 = cbase + ct * TC;
    __syncthreads();  // prev epilogue done with d2buf/sqB
    if (tid < TC) sqB[tid] = sq[c0 + tid];
#pragma unroll
    for (int i = 0; i < 4; i++)
#pragma unroll
      for (int j = 0; j < 4; j++) acc[i][j] = (f32x4){0.f, 0.f, 0.f, 0.f};

    // prologue: 2 stages x 3 loads = 6 in flight (sqB's load retires with the
    // first counted wait; waits are oldest-first so ledger stays safe).
    stage_rc(xh, r0, c0, 0, stage[0], tid, sstk);
    stage_rc(xh, r0, c0, BK, stage[1], tid, sstk);

    for (int kc = 0; kc < NKC; kc++) {
      if (kc < NKC - 1) { WAITVM(3); } else { WAITVM(0); }
      __builtin_amdgcn_s_barrier();  // buf[kc] landed for all waves

      const _Float16* S = stage[kc & 1];
      f16x8 ah[4], bh[4];
#pragma unroll
      for (int i = 0; i < 4; i++)
        ah[i] = *(const f16x8*)(S + (wr + i * 16 + cl) * BK + pq8);
#pragma unroll
      for (int j = 0; j < 4; j++)
        bh[j] = *(const f16x8*)(S + A_H + (wc + j * 16 + cl) * BK + pq8);
      WAITLGKM0;
      __builtin_amdgcn_s_barrier();  // all waves done reading buf[kc]

      if (kc + 2 < NKC)
        stage_rc(xh, r0, c0, (kc + 2) * BK, stage[kc & 1], tid, sstk);

      __builtin_amdgcn_s_setprio(1);
#pragma unroll
      for (int i = 0; i < 4; i++)
#pragma unroll
        for (int j = 0; j < 4; j++)
          acc[i][j] = __builtin_amdgcn_mfma_f32_16x16x32_f16(ah[i], bh[j], acc[i][j], 0, 0, 0);
      __builtin_amdgcn_s_setprio(0);
    }
    // vmcnt==0, frag reads drained -> stage reusable as d2buf.

    // 4 passes over 32-col strips. Pass p: waves with (wv>>2)==(p>>1) dump
    // their 64-row group for j = (p&1)*2 + {0,1}; owners tid<256 scan.
#pragma unroll
    for (int p = 0; p < 4; p++) {
      if ((wv >> 2) == (p >> 1)) {
#pragma unroll
        for (int jj = 0; jj < 2; jj++) {
          const int j = (p & 1) * 2 + jj;
          const float sb = sqB[wc + j * 16 + cl];
#pragma unroll
          for (int i = 0; i < 4; i++)
#pragma unroll
            for (int r = 0; r < 4; r++) {
              const int row = wr + i * 16 + quad * 4 + r;
              d2buf[row * D2PAD + jj * 16 + cl] =
                  fmaxf(sqA[row] + sb - 2.0f * acc[i][j][r], 0.0f);
            }
        }
      }
      __syncthreads();
      if (tid < TR) {
        const int rg = r0 + tid;
        const float* drow = d2buf + tid * D2PAD;
        const float4 v0 = *(const float4*)(drow + 0), v1 = *(const float4*)(drow + 4);
        const float4 v2 = *(const float4*)(drow + 8), v3 = *(const float4*)(drow + 12);
        const float4 v4 = *(const float4*)(drow + 16), v5 = *(const float4*)(drow + 20);
        const float4 v6 = *(const float4*)(drow + 24), v7 = *(const float4*)(drow + 28);
        const float4 ma = min4(min4(min4(v0, v1), min4(v2, v3)),
                               min4(min4(v4, v5), min4(v6, v7)));
        const float mmin = fminf(fminf(ma.x, ma.y), fminf(ma.z, ma.w));
        if (mmin < th) {
          for (int c = 0; c < 32; c++) {
            const float d2v = drow[c];
            if (d2v >= th) continue;
            const int cg = c0 + p * 32 + c;
            if (cg == rg) continue;
            const unsigned int qd = (unsigned int)(d2v * 64.0f);  // d2<4096 -> 18b
            const unsigned int pv = (qd << 14) | (unsigned int)cg;
            if (pv < listp[tid][CLIST - 1]) {
              int pp = CLIST - 1;
              while (pp > 0 && listp[tid][pp - 1] > pv) {
                listp[tid][pp] = listp[tid][pp - 1];
                pp--;
              }
              listp[tid][pp] = pv;
              th = (float)((listp[tid][CLIST - 1] >> 14) + 1) * 0.015625f;
            }
          }
        }
      }
      __syncthreads();
    }
  }

  if (tid < TR) {
    const unsigned int base = ((unsigned int)part * NPTS + (r0 + tid)) * CLIST;
#pragma unroll
    for (int q = 0; q < CLIST; q++) pk[base + q] = listp[tid][q];
  }
}

// ---------------- k4: exact rerank of merged top-RCAND of 104 candidates --------
__global__ __launch_bounds__(64) void rerank_kernel(const float* __restrict__ x,
                                                    const float* __restrict__ sq,
                                                    const unsigned int* __restrict__ pk,
                                                    int* __restrict__ idx) {
  __shared__ unsigned int pkL[NCAND];
  __shared__ unsigned short candL[RCAND];
  const int row = blockIdx.x, lane = threadIdx.x;

  for (int e = lane; e < NCAND; e += 64) {
    const int part = e / CLIST, pos = e - part * CLIST;
    pkL[e] = pk[((size_t)part * NPTS + row) * CLIST + pos];
  }
  __syncthreads();

  for (int e = lane; e < NCAND; e += 64) {
    const unsigned int v = pkL[e];
    int rank = 0;
    for (int s = 0; s < NCAND; s++) rank += (pkL[s] < v) ? 1 : 0;
    if (rank < RCAND) candL[rank] = (unsigned short)(v & 0x3FFFu);
  }
  __syncthreads();

  const float4 xa = *(const float4*)(x + (size_t)row * DIM + lane * 8);
  const float4 xb = *(const float4*)(x + (size_t)row * DIM + lane * 8 + 4);
  const float sqr = sq[row];

  float dl[KNN]; int il[KNN];
#pragma unroll
  for (int q = 0; q < KNN; q++) { dl[q] = INFINITY; il[q] = 0x7fffffff; }

  for (int k = 0; k < RCAND; k++) {
    const int c = candL[k];
    const float4 ya = *(const float4*)(x + (size_t)c * DIM + lane * 8);
    const float4 yb = *(const float4*)(x + (size_t)c * DIM + lane * 8 + 4);
    float p = xa.x * ya.x;
    p = fmaf(xa.y, ya.y, p); p = fmaf(xa.z, ya.z, p); p = fmaf(xa.w, ya.w, p);
    p = fmaf(xb.x, yb.x, p); p = fmaf(xb.y, yb.y, p);
    p = fmaf(xb.z, yb.z, p); p = fmaf(xb.w, yb.w, p);
#pragma unroll
    for (int off = 32; off > 0; off >>= 1) p += __shfl_xor(p, off);
    const float d2 = sqr + sq[c] - 2.0f * p;
    float dd = sqrtf(fmaxf(d2, 0.0f));
    int cc = c;
#pragma unroll
    for (int q = 0; q < KNN; q++) {
      const bool better = (dd < dl[q]) || (dd == dl[q] && cc < il[q]);
      const float nd = better ? dl[q] : dd;
      const int ni = better ? il[q] : cc;
      dl[q] = better ? dd : dl[q];
      il[q] = better ? cc : il[q];
      dd = nd; cc = ni;
    }
  }
  if (lane == 0) {
#pragma unroll
    for (int q = 0; q < KNN; q++) idx[(size_t)row * KNN + q] = il[q];
  }
}

// ---------------- k5: gather-sum of 10 neighbor rows of xW (f32) ----------------
__global__ __launch_bounds__(128) void gather_kernel(const float* __restrict__ xw,
                                                     const int* __restrict__ idx,
                                                     float* __restrict__ out) {
  const int row = blockIdx.x, tid = threadIdx.x;
  const int* ip = idx + (size_t)row * KNN;
  float4 s = {0.f, 0.f, 0.f, 0.f};
#pragma unroll
  for (int j = 0; j < KNN; j++) {
    const int nb = ip[j] & (NPTS - 1);
    const float4 v = *(const float4*)(xw + (size_t)nb * DIM + tid * 4);
    s.x += v.x; s.y += v.y; s.z += v.z; s.w += v.w;
  }
  *(float4*)(out + (size_t)row * DIM + tid * 4) = s;
}

extern "C" void kernel_launch(void* const* d_in, const int* in_sizes, int n_in,
                              void* d_out, int out_size, void* d_ws, size_t ws_size,
                              hipStream_t stream) {
  const float* x = (const float*)d_in[0];
  const float* A = (const float*)d_in[1];
  float* out = (float*)d_out;
  char* ws = (char*)d_ws;
  float* sq = (float*)(ws + OFF_SQ);
  unsigned int* pk = (unsigned int*)(ws + OFF_PK);
  int* idx = (int*)(ws + OFF_IDX);
  _Float16* xh = (_Float16*)(ws + OFF_XH);
  _Float16* xl = (_Float16*)(ws + OFF_XL);
  _Float16* aht = (_Float16*)(ws + OFF_AHT);
  _Float16* alt = (_Float16*)(ws + OFF_ALT);
  float* xw = (float*)(ws + OFF_XW);

  split_x_kernel<<<NPTS, 64, 0, stream>>>(x, xh, xl, sq);
  split_at_kernel<<<DIM, 64, 0, stream>>>(A, aht, alt);
  xw_kernel<<<(NPTS / TILE) * (DIM / TILE), 256, 0, stream>>>(xh, xl, aht, alt, xw);
  knn_coarse_kernel<<<NPART * (NPTS / TR), 512, 0, stream>>>(xh, sq, pk);
  rerank_kernel<<<NPTS, 64, 0, stream>>>(x, sq, pk, idx);
  gather_kernel<<<NPTS, 128, 0, stream>>>(xw, idx, out);
}